// Round 3
// baseline (406.964 us; speedup 1.0000x reference)
//
#include <hip/hip_runtime.h>

typedef short  bf16x8 __attribute__((ext_vector_type(8)));
typedef float  f32x4  __attribute__((ext_vector_type(4)));

__device__ __forceinline__ unsigned short f2bf(float x) {
    unsigned int u = __float_as_uint(x);
    u += 0x7FFFu + ((u >> 16) & 1u);   // round-to-nearest-even
    return (unsigned short)(u >> 16);
}
__device__ __forceinline__ unsigned int pack2(float lo, float hi) {
    return (unsigned int)f2bf(lo) | ((unsigned int)f2bf(hi) << 16);
}

// ---------------- bf16 MFMA GEMM body, 128x128 tile, K=256 --------------------
// A: fp32 (A_F32, guarded to M rows, lda floats) or bf16 (padded ws, lda shorts).
// Bt: bf16 [*][256] (B transposed). C via LDS-coalesced epilogue:
//   bf16 arena (no row guard, ldc shorts) or fp32 (guarded gm<M, ldc floats).
// EPI: 0=none, 2=+bias, 3=relu(+bias) for gn<256 only.
// SH: 10240 shorts (20480 B) shared staging (As | Bs during K-loop, C after).
template<bool A_F32, bool OUT_BF16, int EPI>
__device__ __forceinline__
void gemm_body(const void* __restrict__ Av, const unsigned short* __restrict__ Bt,
               const float* __restrict__ bias, void* __restrict__ Cout,
               int M, int lda, int ldc, int coff, int mBase, int nBase,
               unsigned short* SH)
{
    constexpr int K = 256, BK = 32, ROWP = 40;  // 80B LDS row stride (conflict-free)
    unsigned short* As = SH;            // 128*40 shorts
    unsigned short* Bs = SH + 5120;     // 128*40 shorts

    const int tid = threadIdx.x;
    const int lane = tid & 63, wid = tid >> 6;
    const int wm = wid & 1, wn = wid >> 1;      // 2x2 waves, each 64x64
    const int l15 = lane & 15, lq = lane >> 4;

    f32x4 acc[4][4];
#pragma unroll
    for (int mt = 0; mt < 4; ++mt)
#pragma unroll
        for (int nt = 0; nt < 4; ++nt)
            acc[mt][nt] = (f32x4){0.f, 0.f, 0.f, 0.f};

    const int srow = tid >> 1;          // 0..127
    const int sseg = (tid & 1) * 16;    // 0 / 16 shorts

    for (int k0 = 0; k0 < K; k0 += BK) {
        if (A_F32) {
            const float* Af = (const float*)Av;
            const int gm = mBase + srow;
            float4 f0, f1, f2, f3;
            if (gm < M) {
                const float4* p = (const float4*)&Af[(size_t)gm * lda + k0 + sseg];
                f0 = p[0]; f1 = p[1]; f2 = p[2]; f3 = p[3];
            } else {
                f0 = f1 = f2 = f3 = make_float4(0.f, 0.f, 0.f, 0.f);
            }
            uint4 o0, o1;
            o0.x = pack2(f0.x, f0.y); o0.y = pack2(f0.z, f0.w);
            o0.z = pack2(f1.x, f1.y); o0.w = pack2(f1.z, f1.w);
            o1.x = pack2(f2.x, f2.y); o1.y = pack2(f2.z, f2.w);
            o1.z = pack2(f3.x, f3.y); o1.w = pack2(f3.z, f3.w);
            *(uint4*)&As[srow * ROWP + sseg]     = o0;
            *(uint4*)&As[srow * ROWP + sseg + 8] = o1;
        } else {
            const unsigned short* Ab = (const unsigned short*)Av;
            const uint4* p = (const uint4*)&Ab[(size_t)(mBase + srow) * lda + k0 + sseg];
            *(uint4*)&As[srow * ROWP + sseg]     = p[0];
            *(uint4*)&As[srow * ROWP + sseg + 8] = p[1];
        }
        {
            const uint4* q = (const uint4*)&Bt[(size_t)(nBase + srow) * 256 + k0 + sseg];
            *(uint4*)&Bs[srow * ROWP + sseg]     = q[0];
            *(uint4*)&Bs[srow * ROWP + sseg + 8] = q[1];
        }
        __syncthreads();

        bf16x8 af[4], bfr[4];
#pragma unroll
        for (int mt = 0; mt < 4; ++mt)
            af[mt] = *(const bf16x8*)&As[(wm * 64 + mt * 16 + l15) * ROWP + lq * 8];
#pragma unroll
        for (int nt = 0; nt < 4; ++nt)
            bfr[nt] = *(const bf16x8*)&Bs[(wn * 64 + nt * 16 + l15) * ROWP + lq * 8];
#pragma unroll
        for (int mt = 0; mt < 4; ++mt)
#pragma unroll
            for (int nt = 0; nt < 4; ++nt)
                acc[mt][nt] = __builtin_amdgcn_mfma_f32_16x16x32_bf16(
                    af[mt], bfr[nt], acc[mt][nt], 0, 0, 0);
        __syncthreads();
    }

    // ---- LDS-coalesced epilogue (reuses SH) ----
    if (OUT_BF16) {
        constexpr int RC = 132;   // shorts; pad keeps ds ops ~2-way (free)
        for (int p = 0; p < 2; ++p) {           // 64-row chunks
            if (wm == p) {
#pragma unroll
                for (int mt = 0; mt < 4; ++mt)
#pragma unroll
                    for (int nt = 0; nt < 4; ++nt) {
                        const int gn = nBase + wn * 64 + nt * 16 + l15;
                        float b = 0.f;
                        if (EPI == 2) b = bias[gn];
                        if (EPI == 3) b = (gn < 256) ? bias[gn] : 0.f;
#pragma unroll
                        for (int i = 0; i < 4; ++i) {
                            const int lr = mt * 16 + lq * 4 + i;
                            float v = acc[mt][nt][i];
                            if (EPI == 2) v += b;
                            if (EPI == 3) { if (gn < 256) v = fmaxf(v + b, 0.f); }
                            SH[lr * RC + wn * 64 + nt * 16 + l15] = f2bf(v);
                        }
                    }
            }
            __syncthreads();
#pragma unroll
            for (int it = 0; it < 4; ++it) {
                const int idx = it * 256 + tid;
                const int row = idx >> 4, c = idx & 15;
                uint4 val = *(const uint4*)&SH[row * RC + c * 8];
                *(uint4*)&((unsigned short*)Cout)[
                    (size_t)(mBase + p * 64 + row) * ldc + coff + nBase + c * 8] = val;
            }
            __syncthreads();
        }
    } else {
        float* Cf = (float*)SH;
        constexpr int RC = 133;   // floats
        for (int p = 0; p < 4; ++p) {           // 32-row chunks
            if (wm == (p >> 1)) {
#pragma unroll
                for (int mt2 = 0; mt2 < 2; ++mt2) {
                    const int mt = (p & 1) * 2 + mt2;
#pragma unroll
                    for (int nt = 0; nt < 4; ++nt) {
                        const int gn = nBase + wn * 64 + nt * 16 + l15;
                        float b = (EPI == 2) ? bias[gn] : 0.f;
#pragma unroll
                        for (int i = 0; i < 4; ++i) {
                            const int lr = mt2 * 16 + lq * 4 + i;
                            float v = acc[mt][nt][i];
                            if (EPI == 2) v += b;
                            Cf[lr * RC + wn * 64 + nt * 16 + l15] = v;
                        }
                    }
                }
            }
            __syncthreads();
#pragma unroll
            for (int it = 0; it < 4; ++it) {
                const int idx = it * 256 + tid;
                const int row = idx >> 5, c = idx & 31;
                const int gm = mBase + p * 32 + row;
                if (gm < M) {
                    float4 val = *(const float4*)&Cf[row * RC + c * 4];
                    *(float4*)&((float*)Cout)[(size_t)gm * ldc + coff + nBase + c * 4] = val;
                }
            }
            __syncthreads();
        }
    }
}

// ---------------- gather SpMM body, 4-way edge unroll -------------------------
template<int TPR, bool RELU>
__device__ __forceinline__
void spmm_body(const unsigned short* __restrict__ x,
               const int* __restrict__ rowptr, const int2* __restrict__ packed,
               float* __restrict__ outf, int N, int ldx, int ldo, int coff, int vbid)
{
    const int rpb = 256 / TPR;
    const int r = vbid * rpb + threadIdx.x / TPR;
    const int lane = threadIdx.x % TPR;
    if (r >= N) return;
    const int beg = rowptr[r], end = rowptr[r + 1];
    const unsigned short* xp = x + lane * 8;
    float a0[8] = {0, 0, 0, 0, 0, 0, 0, 0};
    float a1[8] = {0, 0, 0, 0, 0, 0, 0, 0};
    int i = beg;
    for (; i + 3 < end; i += 4) {
        int2 e0 = packed[i], e1 = packed[i + 1], e2 = packed[i + 2], e3 = packed[i + 3];
        uint4 v0 = *(const uint4*)&xp[(size_t)e0.x * ldx];
        uint4 v1 = *(const uint4*)&xp[(size_t)e1.x * ldx];
        uint4 v2 = *(const uint4*)&xp[(size_t)e2.x * ldx];
        uint4 v3 = *(const uint4*)&xp[(size_t)e3.x * ldx];
        float w0 = __int_as_float(e0.y), w1 = __int_as_float(e1.y);
        float w2 = __int_as_float(e2.y), w3 = __int_as_float(e3.y);
        unsigned int s0[4] = {v0.x, v0.y, v0.z, v0.w};
        unsigned int s1[4] = {v1.x, v1.y, v1.z, v1.w};
        unsigned int s2[4] = {v2.x, v2.y, v2.z, v2.w};
        unsigned int s3[4] = {v3.x, v3.y, v3.z, v3.w};
#pragma unroll
        for (int j = 0; j < 4; ++j) {
            a0[2 * j]     = fmaf(w0, __uint_as_float(s0[j] << 16),         a0[2 * j]);
            a0[2 * j + 1] = fmaf(w0, __uint_as_float(s0[j] & 0xFFFF0000u), a0[2 * j + 1]);
            a1[2 * j]     = fmaf(w1, __uint_as_float(s1[j] << 16),         a1[2 * j]);
            a1[2 * j + 1] = fmaf(w1, __uint_as_float(s1[j] & 0xFFFF0000u), a1[2 * j + 1]);
            a0[2 * j]     = fmaf(w2, __uint_as_float(s2[j] << 16),         a0[2 * j]);
            a0[2 * j + 1] = fmaf(w2, __uint_as_float(s2[j] & 0xFFFF0000u), a0[2 * j + 1]);
            a1[2 * j]     = fmaf(w3, __uint_as_float(s3[j] << 16),         a1[2 * j]);
            a1[2 * j + 1] = fmaf(w3, __uint_as_float(s3[j] & 0xFFFF0000u), a1[2 * j + 1]);
        }
    }
    for (; i + 1 < end; i += 2) {
        int2 e0 = packed[i], e1 = packed[i + 1];
        uint4 v0 = *(const uint4*)&xp[(size_t)e0.x * ldx];
        uint4 v1 = *(const uint4*)&xp[(size_t)e1.x * ldx];
        float w0 = __int_as_float(e0.y), w1 = __int_as_float(e1.y);
        unsigned int s0[4] = {v0.x, v0.y, v0.z, v0.w};
        unsigned int s1[4] = {v1.x, v1.y, v1.z, v1.w};
#pragma unroll
        for (int j = 0; j < 4; ++j) {
            a0[2 * j]     = fmaf(w0, __uint_as_float(s0[j] << 16),         a0[2 * j]);
            a0[2 * j + 1] = fmaf(w0, __uint_as_float(s0[j] & 0xFFFF0000u), a0[2 * j + 1]);
            a1[2 * j]     = fmaf(w1, __uint_as_float(s1[j] << 16),         a1[2 * j]);
            a1[2 * j + 1] = fmaf(w1, __uint_as_float(s1[j] & 0xFFFF0000u), a1[2 * j + 1]);
        }
    }
    if (i < end) {
        int2 e0 = packed[i];
        uint4 v0 = *(const uint4*)&xp[(size_t)e0.x * ldx];
        float w0 = __int_as_float(e0.y);
        unsigned int s0[4] = {v0.x, v0.y, v0.z, v0.w};
#pragma unroll
        for (int j = 0; j < 4; ++j) {
            a0[2 * j]     = fmaf(w0, __uint_as_float(s0[j] << 16),         a0[2 * j]);
            a0[2 * j + 1] = fmaf(w0, __uint_as_float(s0[j] & 0xFFFF0000u), a0[2 * j + 1]);
        }
    }
    float acc[8];
#pragma unroll
    for (int j = 0; j < 8; ++j) {
        acc[j] = a0[j] + a1[j];
        if (RELU) acc[j] = fmaxf(acc[j], 0.f);
    }
    float* o = &outf[(size_t)r * ldo + coff + lane * 8];
    *(float4*)o       = make_float4(acc[0], acc[1], acc[2], acc[3]);
    *(float4*)(o + 4) = make_float4(acc[4], acc[5], acc[6], acc[7]);
}

// ---------------- prep: weight transpose-convert + rowptr zero ----------------
__global__ __launch_bounds__(256)
void prep_kernel(const float* __restrict__ mw1, const float* __restrict__ W1,
                 const float* __restrict__ mw2, const float* __restrict__ W2,
                 unsigned short* __restrict__ warena, int* __restrict__ rowptr, int n1)
{
    int i = blockIdx.x * 256 + threadIdx.x;
    if (i < n1) rowptr[i] = 0;
    if (i >= 768 * 256) return;
    int r = i >> 8, k = i & 255;
    float v;
    if (r < 256)      v = mw1[k * 256 + r];
    else if (r < 512) v = W1[k * 256 + (r - 256)];
    else if (r < 640) v = mw2[k * 128 + (r - 512)];
    else              v = W2[k * 128 + (r - 640)];
    warena[i] = f2bf(v);
}

// ---------------- fused gemmA + histogram -------------------------------------
__global__ __launch_bounds__(256)
void gemmA_hist(const float* __restrict__ X,
                const unsigned short* __restrict__ Wc,
                const float* __restrict__ mb1, unsigned short* __restrict__ S1Y1,
                int M, int G,
                const int* __restrict__ dst, int* __restrict__ cnt, int E)
{
    __shared__ __align__(16) unsigned short SH[10240];
    const int bid = blockIdx.x;
    const int r = bid % 3, g = bid / 3;
    if (bid < 3 * G && r == 0) {
        // sibling-adjacent decode: 4 column tiles of one row panel are adjacent
        const int mBase = (g >> 2) * 128, nBase = (g & 3) * 128;
        gemm_body<true, true, 3>(X, Wc, mb1, S1Y1, M, 256, 512, 0,
                                 mBase, nBase, SH);
    } else {
        int hid = (bid < 3 * G) ? (2 * g + (r - 1)) : (2 * G + (bid - 3 * G));
        int e = hid * 256 + threadIdx.x;
        if (e < E) atomicAdd(&cnt[dst[e]], 1);
    }
}

// ---------------- fused SpMM1 + K2 (both ready after scatter/gemmA) -----------
// K2 blocks (G2) interleaved 1:17 with SpMM1 blocks; MFMA hides in gather stalls.
__global__ __launch_bounds__(256)
void spmm1_k2(const unsigned short* __restrict__ x,
              const int* __restrict__ rowptr, const int2* __restrict__ packed,
              float* __restrict__ out, int N, int G2,
              const unsigned short* __restrict__ S1Y1,
              const unsigned short* __restrict__ mw2t,
              const float* __restrict__ mb2, int ldc)
{
    __shared__ __align__(16) unsigned short SH[10240];
    const int bid = blockIdx.x;
    const int q = bid / 17;
    if (bid % 17 == 0 && q < G2) {
        gemm_body<false, false, 2>(S1Y1, mw2t, mb2, out, N, 512, ldc, 0,
                                   q * 128, 0, SH);
    } else {
        int below = (bid % 17 == 0) ? q : q + 1;
        if (below > G2) below = G2;
        spmm_body<32, true>(x, rowptr, packed, out, N, 512, ldc, 128, bid - below);
    }
}

// ---------------- K4 standalone (A fp32 from out h1 slice) --------------------
__global__ __launch_bounds__(256)
void gemm_k4(const float* __restrict__ A, const unsigned short* __restrict__ Bt,
             unsigned short* __restrict__ Cout, int M, int lda, int ldc)
{
    __shared__ __align__(16) unsigned short SH[10240];
    gemm_body<true, true, 0>(A, Bt, nullptr, Cout, M, lda, ldc, 0,
                             blockIdx.x * 128, 0, SH);
}

// ---------------- SpMM2 standalone --------------------------------------------
__global__ __launch_bounds__(256)
void spmm2_kernel(const unsigned short* __restrict__ x,
                  const int* __restrict__ rowptr, const int2* __restrict__ packed,
                  float* __restrict__ out, int N, int ldo, int coff)
{
    spmm_body<16, false>(x, rowptr, packed, out, N, 128, ldo, coff, blockIdx.x);
}

// ---------------- CSR build ---------------------------------------------------
__global__ __launch_bounds__(256)
void reduce_chunks(const int* __restrict__ cnt, int* __restrict__ bsum, int n)
{
    __shared__ int s[256];
    int i = blockIdx.x * 256 + threadIdx.x;
    s[threadIdx.x] = (i < n) ? cnt[i] : 0;
    __syncthreads();
    for (int o = 128; o > 0; o >>= 1) {
        if (threadIdx.x < o) s[threadIdx.x] += s[threadIdx.x + o];
        __syncthreads();
    }
    if (threadIdx.x == 0) bsum[blockIdx.x] = s[0];
}

__global__ __launch_bounds__(256)
void scan_bsum(int* __restrict__ bsum, int nb, int* __restrict__ rowptr, int n)
{
    __shared__ int s[256];
    int t = threadIdx.x;
    int v = (t < nb) ? bsum[t] : 0;
    s[t] = v;
    __syncthreads();
    for (int o = 1; o < 256; o <<= 1) {
        int u = (t >= o) ? s[t - o] : 0;
        __syncthreads();
        s[t] += u;
        __syncthreads();
    }
    if (t < nb) bsum[t] = s[t] - v;
    if (t == 255) rowptr[n] = s[255];
}

__global__ __launch_bounds__(256)
void scan_write(const int* cnt, const int* __restrict__ bsum,
                int* rowptr, int* __restrict__ pos, int n)
{
    __shared__ int s[256];
    int t = threadIdx.x;
    int i = blockIdx.x * 256 + t;
    int v = (i < n) ? cnt[i] : 0;
    s[t] = v;
    __syncthreads();
    for (int o = 1; o < 256; o <<= 1) {
        int u = (t >= o) ? s[t - o] : 0;
        __syncthreads();
        s[t] += u;
        __syncthreads();
    }
    if (i < n) {
        int ex = bsum[blockIdx.x] + s[t] - v;
        rowptr[i] = ex;
        pos[i] = ex;
    }
}

__global__ __launch_bounds__(256)
void scatter_kernel(const int* __restrict__ src, const int* __restrict__ dst,
                    const float* __restrict__ w, int* __restrict__ pos,
                    int2* __restrict__ packed, int E)
{
    int e = blockIdx.x * 256 + threadIdx.x;
    if (e >= E) return;
    int p = atomicAdd(&pos[dst[e]], 1);
    packed[p] = make_int2(src[e], __float_as_int(w[e]));
}

// ---------------- launch ------------------------------------------------------
extern "C" void kernel_launch(void* const* d_in, const int* in_sizes, int n_in,
                              void* d_out, int out_size, void* d_ws, size_t ws_size,
                              hipStream_t stream)
{
    const float* X    = (const float*)d_in[0];
    const int*   esrc = (const int*)  d_in[1];
    const int*   edst = (const int*)  d_in[2];
    const float* ew   = (const float*)d_in[3];
    const float* W1   = (const float*)d_in[4];
    const float* W2   = (const float*)d_in[5];
    const float* mw1  = (const float*)d_in[6];
    const float* mb1  = (const float*)d_in[7];
    const float* mw2  = (const float*)d_in[8];
    const float* mb2  = (const float*)d_in[9];

    const int IN_F = 256, HID_F = 256, OUT_F = 128;
    const int N  = in_sizes[0] / IN_F;
    const int E  = in_sizes[1];
    const int LD = OUT_F + HID_F + OUT_F;       // 512
    const int Mp = (N + 127) & ~127;

    float* out = (float*)d_out;

    // workspace (shorts)
    unsigned short* S1Y1  = (unsigned short*)d_ws;          // [Mp][512]: S1 | Y1
    unsigned short* gb    = S1Y1 + (size_t)Mp * 512;        // [Mp][128]
    unsigned short* warena = gb  + (size_t)Mp * 128;        // [768][256]
    unsigned short* Wc   = warena;                          // [512][256]
    unsigned short* mw2t = warena + 512 * 256;              // [128][256]
    unsigned short* w2t  = warena + 640 * 256;              // [128][256]
    int* rowptr = (int*)(warena + 768 * 256);               // N+1
    int* bsum   = rowptr + (((N + 1) + 3) & ~3);            // 256
    int* pos    = bsum + 256;                               // N
    int2* packed = (int2*)(pos + ((N + 1) & ~1));           // E

    dim3 blk(256);
    const int nb = (N + 255) / 256;         // <=256 for scan_bsum
    const int mT = Mp / 128;                // 391
    const int He = (E + 255) / 256;         // hist/scatter blocks: 3125

    // prep: weight conversion + rowptr zeroing
    prep_kernel<<<768, blk, 0, stream>>>(mw1, W1, mw2, W2, warena, rowptr, N + 1);

    // fused gemmA + hist: [S1 | Y1] = X @ [mw1 | W1] (relu+b1 on first 256 cols)
    {
        const int G = mT * 4;
        int grid = 3 * G + ((He > 2 * G) ? (He - 2 * G) : 0);
        gemmA_hist<<<grid, blk, 0, stream>>>(
            X, Wc, mb1, S1Y1, N, G, edst, rowptr, E);
    }

    // CSR scans
    reduce_chunks<<<nb, blk, 0, stream>>>(rowptr, bsum, N);
    scan_bsum<<<1, blk, 0, stream>>>(bsum, nb, rowptr, N);
    scan_write<<<nb, blk, 0, stream>>>(rowptr, bsum, rowptr, pos, N);

    // scatter: pack CSR edges
    scatter_kernel<<<He, blk, 0, stream>>>(esrc, edst, ew, pos, packed, E);

    // fused SpMM1 + K2:
    //   SpMM1: h1 = relu(A @ Y1) -> out[:,128:384] fp32
    //   K2:    out[:,0:128] = S1 @ mw2 + b2
    {
        const int Gs = (N + 7) / 8;
        spmm1_k2<<<Gs + mT, blk, 0, stream>>>(
            S1Y1 + 256, rowptr, packed, out, N, mT, S1Y1, mw2t, mb2, LD);
    }

    // K4: gb = h1 @ W2 (bf16), A read fp32 from out h1 slice (L3-warm)
    gemm_k4<<<mT, blk, 0, stream>>>(out + OUT_F, w2t, gb, N, LD, 128);

    // SpMM2: out[:,384:512] = A @ g (fp32)
    spmm2_kernel<<<(N + 15) / 16, blk, 0, stream>>>(
        gb, rowptr, packed, out, N, LD, OUT_F + HID_F);
}

// Round 4
// 384.083 us; speedup vs baseline: 1.0596x; 1.0596x over previous
//
#include <hip/hip_runtime.h>

typedef short  bf16x8 __attribute__((ext_vector_type(8)));
typedef float  f32x4  __attribute__((ext_vector_type(4)));

__device__ __forceinline__ unsigned short f2bf(float x) {
    unsigned int u = __float_as_uint(x);
    u += 0x7FFFu + ((u >> 16) & 1u);   // round-to-nearest-even
    return (unsigned short)(u >> 16);
}
__device__ __forceinline__ unsigned int pack2(float lo, float hi) {
    return (unsigned int)f2bf(lo) | ((unsigned int)f2bf(hi) << 16);
}
__device__ __forceinline__ void gload_lds16(const void* g, void* l) {
    __builtin_amdgcn_global_load_lds(
        (const __attribute__((address_space(1))) void*)g,
        (__attribute__((address_space(3))) void*)l, 16, 0, 0);
}

// ---------------- bf16 MFMA GEMM body, 128x128 tile, K=256 --------------------
// A,B both bf16. Staging via global_load_lds (16B/lane), double-buffered LDS,
// stage(t+1) issued before compute(t) so HBM latency hides under MFMA.
// LDS layout linear [128][32] shorts per buffer; XOR-unit swizzle applied on the
// GLOBAL source (rule: linear dest + inv-swz source + swz read). Read conflicts
// ~2-way (free). SH: 16384 shorts = 32 KB (As[2] | Bs[2]).
// C: bf16 (unguarded, A rows padded) or fp32 (guarded gm<M).
// EPI: 0=none, 2=+bias, 3=relu(+bias) for gn<256 only.
template<bool OUT_BF16, int EPI>
__device__ __forceinline__
void gemm_body(const unsigned short* __restrict__ Ab,
               const unsigned short* __restrict__ Bt,
               const float* __restrict__ bias, void* __restrict__ Cout,
               int M, int lda, int ldc, int coff, int mBase, int nBase,
               unsigned short* SH)
{
    constexpr int BK = 32, NT = 8;      // K = 256
    const int tid = threadIdx.x;
    const int lane = tid & 63, wid = tid >> 6;
    const int wm = wid & 1, wn = wid >> 1;      // 2x2 waves, each 64x64
    const int l15 = lane & 15, lq = lane >> 4;
    const int swz = (l15 >> 1) & 3;             // read-side unit swizzle

    unsigned short* As = SH;            // [2][128*32]
    unsigned short* Bs = SH + 8192;     // [2][128*32]

    const int sr = lane >> 2, su = lane & 3;    // staging row/unit within chunk

    f32x4 acc[4][4];
#pragma unroll
    for (int mt = 0; mt < 4; ++mt)
#pragma unroll
        for (int nt = 0; nt < 4; ++nt)
            acc[mt][nt] = (f32x4){0.f, 0.f, 0.f, 0.f};

    // stage K-step k0 into buffer b: each wave covers 32 rows of As and Bs.
    // gload_lds dest is wave-uniform base + lane*16B (linear); global source
    // pre-swizzled: LDS[r][u] <- global[r][u ^ ((r>>1)&3)]
    auto stage = [&](int b, int k0) {
#pragma unroll
        for (int s = 0; s < 2; ++s) {
            const int R = wid * 32 + s * 16;
            const int r = R + sr;
            const int gu = su ^ ((r >> 1) & 3);
            gload_lds16(Ab + (size_t)(mBase + r) * lda + k0 + gu * 8,
                        &As[b * 4096 + R * 32]);
            gload_lds16(Bt + (size_t)(nBase + r) * 256 + k0 + gu * 8,
                        &Bs[b * 4096 + R * 32]);
        }
    };

    stage(0, 0);
    __syncthreads();
#pragma unroll
    for (int t = 0; t < NT; ++t) {
        const int b = t & 1;
        if (t < NT - 1) stage(b ^ 1, (t + 1) * BK);   // prefetch next K-step
        bf16x8 af[4], bfr[4];
#pragma unroll
        for (int mt = 0; mt < 4; ++mt)
            af[mt] = *(const bf16x8*)&As[b * 4096 +
                        (wm * 64 + mt * 16 + l15) * 32 + (lq ^ swz) * 8];
#pragma unroll
        for (int nt = 0; nt < 4; ++nt)
            bfr[nt] = *(const bf16x8*)&Bs[b * 4096 +
                        (wn * 64 + nt * 16 + l15) * 32 + (lq ^ swz) * 8];
#pragma unroll
        for (int mt = 0; mt < 4; ++mt)
#pragma unroll
            for (int nt = 0; nt < 4; ++nt)
                acc[mt][nt] = __builtin_amdgcn_mfma_f32_16x16x32_bf16(
                    af[mt], bfr[nt], acc[mt][nt], 0, 0, 0);
        __syncthreads();   // drains prefetch (had MFMA-time) + read fence
    }

#pragma unroll
    for (int mt = 0; mt < 4; ++mt) {
#pragma unroll
        for (int nt = 0; nt < 4; ++nt) {
            const int gn = nBase + wn * 64 + nt * 16 + l15;
#pragma unroll
            for (int i = 0; i < 4; ++i) {
                const int gm = mBase + wm * 64 + mt * 16 + lq * 4 + i;
                float v = acc[mt][nt][i];
                if (EPI == 2) v += bias[gn];
                if (EPI == 3) { if (gn < 256) v = fmaxf(v + bias[gn], 0.f); }
                if (OUT_BF16) {
                    ((unsigned short*)Cout)[(size_t)gm * ldc + coff + gn] = f2bf(v);
                } else {
                    if (gm < M)
                        ((float*)Cout)[(size_t)gm * ldc + coff + gn] = v;
                }
            }
        }
    }
}

// ---------------- prep: weight transpose-convert + rowptr zero + X->bf16 ------
__global__ __launch_bounds__(256)
void prep_kernel(const float* __restrict__ mw1, const float* __restrict__ W1,
                 const float* __restrict__ mw2, const float* __restrict__ W2,
                 unsigned short* __restrict__ warena, int* __restrict__ rowptr, int n1,
                 const float* __restrict__ X, unsigned short* __restrict__ Xb,
                 int N, int Mp)
{
    const int bid = blockIdx.x;
    if (bid < 768) {
        int i = bid * 256 + threadIdx.x;
        if (i < n1) rowptr[i] = 0;
        int r = i >> 8, k = i & 255;
        float v;
        if (r < 256)      v = mw1[k * 256 + r];
        else if (r < 512) v = W1[k * 256 + (r - 256)];
        else if (r < 640) v = mw2[k * 128 + (r - 512)];
        else              v = W2[k * 128 + (r - 640)];
        warena[i] = f2bf(v);
    } else {
        int j = (bid - 768) * 256 + threadIdx.x;
        if (j >= Mp * 32) return;
        int row = j >> 5, seg = (j & 31) << 3;
        uint4 o;
        if (row < N) {
            const float4* p = (const float4*)&X[(size_t)row * 256 + seg];
            float4 f0 = p[0], f1 = p[1];
            o.x = pack2(f0.x, f0.y); o.y = pack2(f0.z, f0.w);
            o.z = pack2(f1.x, f1.y); o.w = pack2(f1.z, f1.w);
        } else {
            o = make_uint4(0u, 0u, 0u, 0u);
        }
        *(uint4*)&Xb[(size_t)row * 256 + seg] = o;
    }
}

// ---------------- fused gemmA + histogram -------------------------------------
// gemm roles 1:2 with hist roles; hist atomics hide under MFMA.
__global__ __launch_bounds__(256)
void gemmA_hist(const unsigned short* __restrict__ Xb,
                const unsigned short* __restrict__ Wc,
                const float* __restrict__ mb1, unsigned short* __restrict__ S1Y1,
                int M, int G,
                const int* __restrict__ dst, int* __restrict__ cnt, int E)
{
    __shared__ __align__(16) unsigned short SH[16384];
    const int bid = blockIdx.x;
    const int r = bid % 3, g = bid / 3;
    if (bid < 3 * G && r == 0) {
        // sibling-adjacent decode: 4 column tiles of one row panel adjacent (L2)
        const int mBase = (g >> 2) * 128, nBase = (g & 3) * 128;
        gemm_body<true, 3>(Xb, Wc, mb1, S1Y1, M, 256, 512, 0, mBase, nBase, SH);
    } else {
        int hid = (bid < 3 * G) ? (2 * g + (r - 1)) : (2 * G + (bid - 3 * G));
        int e = hid * 256 + threadIdx.x;
        if (e < E) atomicAdd(&cnt[dst[e]], 1);
    }
}

// ---------------- fused K2 + scatter (1:8) ------------------------------------
__global__ __launch_bounds__(256)
void k2_scatter(const unsigned short* __restrict__ S1Y1,
                const unsigned short* __restrict__ mw2t,
                const float* __restrict__ mb2, float* __restrict__ out,
                int M, int ldc, int G,
                const int* __restrict__ src, const int* __restrict__ dst,
                const float* __restrict__ w, int* __restrict__ pos,
                int2* __restrict__ packed, int E)
{
    __shared__ __align__(16) unsigned short SH[16384];
    const int bid = blockIdx.x;
    const int r = bid % 9, g = bid / 9;
    if (bid < 9 * G && r == 0) {
        gemm_body<false, 2>(S1Y1, mw2t, mb2, out, M, 512, ldc, 0,
                            g * 128, 0, SH);
    } else {
        int sid = (bid < 9 * G) ? (bid - g - 1) : (8 * G + (bid - 9 * G));
        int e = sid * 256 + threadIdx.x;
        if (e >= E) return;
        int p = atomicAdd(&pos[dst[e]], 1);
        packed[p] = make_int2(src[e], __float_as_int(w[e]));
    }
}

// ---------------- K4 standalone (A bf16 = h1b) --------------------------------
__global__ __launch_bounds__(256)
void gemm_k4(const unsigned short* __restrict__ A, const unsigned short* __restrict__ Bt,
             unsigned short* __restrict__ Cout, int M, int lda, int ldc)
{
    __shared__ __align__(16) unsigned short SH[16384];
    gemm_body<true, 0>(A, Bt, nullptr, Cout, M, lda, ldc, 0,
                       blockIdx.x * 128, 0, SH);
}

// ---------------- CSR build ---------------------------------------------------
__global__ __launch_bounds__(256)
void reduce_chunks(const int* __restrict__ cnt, int* __restrict__ bsum, int n)
{
    __shared__ int s[256];
    int i = blockIdx.x * 256 + threadIdx.x;
    s[threadIdx.x] = (i < n) ? cnt[i] : 0;
    __syncthreads();
    for (int o = 128; o > 0; o >>= 1) {
        if (threadIdx.x < o) s[threadIdx.x] += s[threadIdx.x + o];
        __syncthreads();
    }
    if (threadIdx.x == 0) bsum[blockIdx.x] = s[0];
}

__global__ __launch_bounds__(256)
void scan_bsum(int* __restrict__ bsum, int nb, int* __restrict__ rowptr, int n)
{
    __shared__ int s[256];
    int t = threadIdx.x;
    int v = (t < nb) ? bsum[t] : 0;
    s[t] = v;
    __syncthreads();
    for (int o = 1; o < 256; o <<= 1) {
        int u = (t >= o) ? s[t - o] : 0;
        __syncthreads();
        s[t] += u;
        __syncthreads();
    }
    if (t < nb) bsum[t] = s[t] - v;
    if (t == 255) rowptr[n] = s[255];
}

__global__ __launch_bounds__(256)
void scan_write(const int* cnt, const int* __restrict__ bsum,
                int* rowptr, int* __restrict__ pos, int n)
{
    __shared__ int s[256];
    int t = threadIdx.x;
    int i = blockIdx.x * 256 + t;
    int v = (i < n) ? cnt[i] : 0;
    s[t] = v;
    __syncthreads();
    for (int o = 1; o < 256; o <<= 1) {
        int u = (t >= o) ? s[t - o] : 0;
        __syncthreads();
        s[t] += u;
        __syncthreads();
    }
    if (i < n) {
        int ex = bsum[blockIdx.x] + s[t] - v;
        rowptr[i] = ex;
        pos[i] = ex;
    }
}

// ---------------- gather SpMM over bf16 rows, 4-way edge unroll ---------------
template<int TPR, bool RELU, bool DUAL>
__global__ __launch_bounds__(256)
void spmm_csr_bf16(const unsigned short* __restrict__ x,
                   const int* __restrict__ rowptr, const int2* __restrict__ packed,
                   float* __restrict__ outf, unsigned short* __restrict__ outb,
                   int N, int ldx, int ldo, int coff, int ldd)
{
    const int rpb = 256 / TPR;
    const int r = blockIdx.x * rpb + threadIdx.x / TPR;
    const int lane = threadIdx.x % TPR;
    if (r >= N) return;
    const int beg = rowptr[r], end = rowptr[r + 1];
    const unsigned short* xp = x + lane * 8;
    float a0[8] = {0, 0, 0, 0, 0, 0, 0, 0};
    float a1[8] = {0, 0, 0, 0, 0, 0, 0, 0};
    int i = beg;
    for (; i + 3 < end; i += 4) {
        int2 e0 = packed[i], e1 = packed[i + 1], e2 = packed[i + 2], e3 = packed[i + 3];
        uint4 v0 = *(const uint4*)&xp[(size_t)e0.x * ldx];
        uint4 v1 = *(const uint4*)&xp[(size_t)e1.x * ldx];
        uint4 v2 = *(const uint4*)&xp[(size_t)e2.x * ldx];
        uint4 v3 = *(const uint4*)&xp[(size_t)e3.x * ldx];
        float w0 = __int_as_float(e0.y), w1 = __int_as_float(e1.y);
        float w2 = __int_as_float(e2.y), w3 = __int_as_float(e3.y);
        unsigned int s0[4] = {v0.x, v0.y, v0.z, v0.w};
        unsigned int s1[4] = {v1.x, v1.y, v1.z, v1.w};
        unsigned int s2[4] = {v2.x, v2.y, v2.z, v2.w};
        unsigned int s3[4] = {v3.x, v3.y, v3.z, v3.w};
#pragma unroll
        for (int j = 0; j < 4; ++j) {
            a0[2 * j]     = fmaf(w0, __uint_as_float(s0[j] << 16),         a0[2 * j]);
            a0[2 * j + 1] = fmaf(w0, __uint_as_float(s0[j] & 0xFFFF0000u), a0[2 * j + 1]);
            a1[2 * j]     = fmaf(w1, __uint_as_float(s1[j] << 16),         a1[2 * j]);
            a1[2 * j + 1] = fmaf(w1, __uint_as_float(s1[j] & 0xFFFF0000u), a1[2 * j + 1]);
            a0[2 * j]     = fmaf(w2, __uint_as_float(s2[j] << 16),         a0[2 * j]);
            a0[2 * j + 1] = fmaf(w2, __uint_as_float(s2[j] & 0xFFFF0000u), a0[2 * j + 1]);
            a1[2 * j]     = fmaf(w3, __uint_as_float(s3[j] << 16),         a1[2 * j]);
            a1[2 * j + 1] = fmaf(w3, __uint_as_float(s3[j] & 0xFFFF0000u), a1[2 * j + 1]);
        }
    }
    for (; i + 1 < end; i += 2) {
        int2 e0 = packed[i], e1 = packed[i + 1];
        uint4 v0 = *(const uint4*)&xp[(size_t)e0.x * ldx];
        uint4 v1 = *(const uint4*)&xp[(size_t)e1.x * ldx];
        float w0 = __int_as_float(e0.y), w1 = __int_as_float(e1.y);
        unsigned int s0[4] = {v0.x, v0.y, v0.z, v0.w};
        unsigned int s1[4] = {v1.x, v1.y, v1.z, v1.w};
#pragma unroll
        for (int j = 0; j < 4; ++j) {
            a0[2 * j]     = fmaf(w0, __uint_as_float(s0[j] << 16),         a0[2 * j]);
            a0[2 * j + 1] = fmaf(w0, __uint_as_float(s0[j] & 0xFFFF0000u), a0[2 * j + 1]);
            a1[2 * j]     = fmaf(w1, __uint_as_float(s1[j] << 16),         a1[2 * j]);
            a1[2 * j + 1] = fmaf(w1, __uint_as_float(s1[j] & 0xFFFF0000u), a1[2 * j + 1]);
        }
    }
    if (i < end) {
        int2 e0 = packed[i];
        uint4 v0 = *(const uint4*)&xp[(size_t)e0.x * ldx];
        float w0 = __int_as_float(e0.y);
        unsigned int s0[4] = {v0.x, v0.y, v0.z, v0.w};
#pragma unroll
        for (int j = 0; j < 4; ++j) {
            a0[2 * j]     = fmaf(w0, __uint_as_float(s0[j] << 16),         a0[2 * j]);
            a0[2 * j + 1] = fmaf(w0, __uint_as_float(s0[j] & 0xFFFF0000u), a0[2 * j + 1]);
        }
    }
    float acc[8];
#pragma unroll
    for (int j = 0; j < 8; ++j) {
        acc[j] = a0[j] + a1[j];
        if (RELU) acc[j] = fmaxf(acc[j], 0.f);
    }
    float* o = &outf[(size_t)r * ldo + coff + lane * 8];
    *(float4*)o       = make_float4(acc[0], acc[1], acc[2], acc[3]);
    *(float4*)(o + 4) = make_float4(acc[4], acc[5], acc[6], acc[7]);
    if (DUAL) {
        uint4 p;
        p.x = pack2(acc[0], acc[1]); p.y = pack2(acc[2], acc[3]);
        p.z = pack2(acc[4], acc[5]); p.w = pack2(acc[6], acc[7]);
        *(uint4*)&outb[(size_t)r * ldd + lane * 8] = p;
    }
}

// ---------------- launch ------------------------------------------------------
extern "C" void kernel_launch(void* const* d_in, const int* in_sizes, int n_in,
                              void* d_out, int out_size, void* d_ws, size_t ws_size,
                              hipStream_t stream)
{
    const float* X    = (const float*)d_in[0];
    const int*   esrc = (const int*)  d_in[1];
    const int*   edst = (const int*)  d_in[2];
    const float* ew   = (const float*)d_in[3];
    const float* W1   = (const float*)d_in[4];
    const float* W2   = (const float*)d_in[5];
    const float* mw1  = (const float*)d_in[6];
    const float* mb1  = (const float*)d_in[7];
    const float* mw2  = (const float*)d_in[8];
    const float* mb2  = (const float*)d_in[9];

    const int IN_F = 256, HID_F = 256, OUT_F = 128;
    const int N  = in_sizes[0] / IN_F;
    const int E  = in_sizes[1];
    const int LD = OUT_F + HID_F + OUT_F;       // 512
    const int Mp = (N + 127) & ~127;

    float* out = (float*)d_out;

    // workspace (shorts)
    unsigned short* S1Y1  = (unsigned short*)d_ws;          // [Mp][512]: S1 | Y1
    unsigned short* Xb    = S1Y1 + (size_t)Mp * 512;        // [Mp][256] X bf16; reused as h1b after gemmA... kept separate below
    unsigned short* h1b   = Xb;                             // h1 bf16 reuses Xb slot (Xb dead after gemmA)
    unsigned short* gb    = Xb   + (size_t)Mp * 256;        // [Mp][128]
    unsigned short* warena = gb  + (size_t)Mp * 128;        // [768][256]
    unsigned short* Wc   = warena;                          // [512][256]
    unsigned short* mw2t = warena + 512 * 256;              // [128][256]
    unsigned short* w2t  = warena + 640 * 256;              // [128][256]
    int* rowptr = (int*)(warena + 768 * 256);               // N+1
    int* bsum   = rowptr + (((N + 1) + 3) & ~3);            // 256
    int* pos    = bsum + 256;                               // N
    int2* packed = (int2*)(pos + ((N + 1) & ~1));           // E

    dim3 blk(256);
    const int nb = (N + 255) / 256;         // <=256 for scan_bsum
    const int mT = Mp / 128;                // 391
    const int He = (E + 255) / 256;         // hist/scatter blocks

    // prep: weight conversion + rowptr zeroing + X fp32->bf16 (rows>=N zeroed)
    prep_kernel<<<768 + Mp / 8, blk, 0, stream>>>(
        mw1, W1, mw2, W2, warena, rowptr, N + 1, X, Xb, N, Mp);

    // fused gemmA + hist: [S1 | Y1] = X @ [mw1 | W1] (relu+b1 on first 256 cols)
    {
        const int G = mT * 4;
        int grid = 3 * G + ((He > 2 * G) ? (He - 2 * G) : 0);
        gemmA_hist<<<grid, blk, 0, stream>>>(
            Xb, Wc, mb1, S1Y1, N, G, edst, rowptr, E);
    }

    // CSR scans
    reduce_chunks<<<nb, blk, 0, stream>>>(rowptr, bsum, N);
    scan_bsum<<<1, blk, 0, stream>>>(bsum, nb, rowptr, N);
    scan_write<<<nb, blk, 0, stream>>>(rowptr, bsum, rowptr, pos, N);

    // fused K2 + scatter: out[:,0:128] = S1 @ mw2 + b2; packed CSR edges
    {
        const int G = mT;
        int grid = 9 * G + ((He > 8 * G) ? (He - 8 * G) : 0);
        k2_scatter<<<grid, blk, 0, stream>>>(
            S1Y1, mw2t, mb2, out, N, LD, G, esrc, edst, ew, pos, packed, E);
    }

    // SpMM1: h1 = relu(A @ Y1) -> out[:,128:384] fp32 + h1b bf16 (feeds K4)
    spmm_csr_bf16<32, true, true><<<(N + 7) / 8, blk, 0, stream>>>(
        S1Y1 + 256, rowptr, packed, out, h1b, N, 512, LD, OUT_F, 256);

    // K4: gb = h1 @ W2 (bf16 A via global_load_lds; rows>=N garbage but unread)
    gemm_k4<<<mT, blk, 0, stream>>>(h1b, w2t, gb, N, 256, 128);

    // SpMM2: out[:,384:512] = A @ g (fp32)
    spmm_csr_bf16<16, false, false><<<(N + 15) / 16, blk, 0, stream>>>(
        gb, rowptr, packed, out, nullptr, N, 128, LD, OUT_F + HID_F, 0);
}

// Round 5
// 383.259 us; speedup vs baseline: 1.0619x; 1.0022x over previous
//
#include <hip/hip_runtime.h>

typedef short  bf16x8 __attribute__((ext_vector_type(8)));
typedef float  f32x4  __attribute__((ext_vector_type(4)));

__device__ __forceinline__ unsigned short f2bf(float x) {
    unsigned int u = __float_as_uint(x);
    u += 0x7FFFu + ((u >> 16) & 1u);   // round-to-nearest-even
    return (unsigned short)(u >> 16);
}
__device__ __forceinline__ unsigned int pack2(float lo, float hi) {
    return (unsigned int)f2bf(lo) | ((unsigned int)f2bf(hi) << 16);
}
__device__ __forceinline__ void gload_lds16(const void* g, void* l) {
    __builtin_amdgcn_global_load_lds(
        (const __attribute__((address_space(1))) void*)g,
        (__attribute__((address_space(3))) void*)l, 16, 0, 0);
}

// ---------------- bf16 MFMA GEMM body, 128x128 tile, K=256 --------------------
// Unchanged from R4 (verified twice). A,B bf16; global_load_lds staging (16B),
// double-buffered LDS, source-side XOR-unit swizzle, conflict-free reads.
template<bool OUT_BF16, int EPI>
__device__ __forceinline__
void gemm_body(const unsigned short* __restrict__ Ab,
               const unsigned short* __restrict__ Bt,
               const float* __restrict__ bias, void* __restrict__ Cout,
               int M, int lda, int ldc, int coff, int mBase, int nBase,
               unsigned short* SH)
{
    constexpr int BK = 32, NT = 8;      // K = 256
    const int tid = threadIdx.x;
    const int lane = tid & 63, wid = tid >> 6;
    const int wm = wid & 1, wn = wid >> 1;      // 2x2 waves, each 64x64
    const int l15 = lane & 15, lq = lane >> 4;
    const int swz = (l15 >> 1) & 3;             // read-side unit swizzle

    unsigned short* As = SH;            // [2][128*32]
    unsigned short* Bs = SH + 8192;     // [2][128*32]

    const int sr = lane >> 2, su = lane & 3;    // staging row/unit within chunk

    f32x4 acc[4][4];
#pragma unroll
    for (int mt = 0; mt < 4; ++mt)
#pragma unroll
        for (int nt = 0; nt < 4; ++nt)
            acc[mt][nt] = (f32x4){0.f, 0.f, 0.f, 0.f};

    auto stage = [&](int b, int k0) {
#pragma unroll
        for (int s = 0; s < 2; ++s) {
            const int R = wid * 32 + s * 16;
            const int r = R + sr;
            const int gu = su ^ ((r >> 1) & 3);
            gload_lds16(Ab + (size_t)(mBase + r) * lda + k0 + gu * 8,
                        &As[b * 4096 + R * 32]);
            gload_lds16(Bt + (size_t)(nBase + r) * 256 + k0 + gu * 8,
                        &Bs[b * 4096 + R * 32]);
        }
    };

    stage(0, 0);
    __syncthreads();
#pragma unroll
    for (int t = 0; t < NT; ++t) {
        const int b = t & 1;
        if (t < NT - 1) stage(b ^ 1, (t + 1) * BK);   // prefetch next K-step
        bf16x8 af[4], bfr[4];
#pragma unroll
        for (int mt = 0; mt < 4; ++mt)
            af[mt] = *(const bf16x8*)&As[b * 4096 +
                        (wm * 64 + mt * 16 + l15) * 32 + (lq ^ swz) * 8];
#pragma unroll
        for (int nt = 0; nt < 4; ++nt)
            bfr[nt] = *(const bf16x8*)&Bs[b * 4096 +
                        (wn * 64 + nt * 16 + l15) * 32 + (lq ^ swz) * 8];
#pragma unroll
        for (int mt = 0; mt < 4; ++mt)
#pragma unroll
            for (int nt = 0; nt < 4; ++nt)
                acc[mt][nt] = __builtin_amdgcn_mfma_f32_16x16x32_bf16(
                    af[mt], bfr[nt], acc[mt][nt], 0, 0, 0);
        __syncthreads();
    }

#pragma unroll
    for (int mt = 0; mt < 4; ++mt) {
#pragma unroll
        for (int nt = 0; nt < 4; ++nt) {
            const int gn = nBase + wn * 64 + nt * 16 + l15;
#pragma unroll
            for (int i = 0; i < 4; ++i) {
                const int gm = mBase + wm * 64 + mt * 16 + lq * 4 + i;
                float v = acc[mt][nt][i];
                if (EPI == 2) v += bias[gn];
                if (EPI == 3) { if (gn < 256) v = fmaxf(v + bias[gn], 0.f); }
                if (OUT_BF16) {
                    ((unsigned short*)Cout)[(size_t)gm * ldc + coff + gn] = f2bf(v);
                } else {
                    if (gm < M)
                        ((float*)Cout)[(size_t)gm * ldc + coff + gn] = v;
                }
            }
        }
    }
}

// ---------------- D1: prep_all = weight conv + X->bf16 + histogram ------------
// rowptr zeroing moved to a hipMemsetAsync node (no ordering hazard with hist).
__global__ __launch_bounds__(256)
void prep_all(const float* __restrict__ mw1, const float* __restrict__ W1,
              const float* __restrict__ mw2, const float* __restrict__ W2,
              unsigned short* __restrict__ warena,
              const float* __restrict__ X, unsigned short* __restrict__ Xb,
              int N, int Mp,
              const int* __restrict__ dst, int* __restrict__ cnt, int E)
{
    const int bid = blockIdx.x;
    const int xBlocks = Mp / 8;
    if (bid < 768) {
        int i = bid * 256 + threadIdx.x;
        int r = i >> 8, k = i & 255;
        float v;
        if (r < 256)      v = mw1[k * 256 + r];
        else if (r < 512) v = W1[k * 256 + (r - 256)];
        else if (r < 640) v = mw2[k * 128 + (r - 512)];
        else              v = W2[k * 128 + (r - 640)];
        warena[i] = f2bf(v);
    } else if (bid < 768 + xBlocks) {
        int j = (bid - 768) * 256 + threadIdx.x;
        int row = j >> 5, seg = (j & 31) << 3;
        uint4 o;
        if (row < N) {
            const float4* p = (const float4*)&X[(size_t)row * 256 + seg];
            float4 f0 = p[0], f1 = p[1];
            o.x = pack2(f0.x, f0.y); o.y = pack2(f0.z, f0.w);
            o.z = pack2(f1.x, f1.y); o.w = pack2(f1.z, f1.w);
        } else {
            o = make_uint4(0u, 0u, 0u, 0u);
        }
        *(uint4*)&Xb[(size_t)row * 256 + seg] = o;
    } else {
        int e = (bid - 768 - xBlocks) * 256 + threadIdx.x;
        if (e < E) atomicAdd(&cnt[dst[e]], 1);
    }
}

// ---------------- D2: single-dispatch exclusive scan (ticket-master) ----------
// nb <= 256 blocks, all co-resident (196 < 256 CUs). Each block scans its 256
// counts; last-arriving block scans the per-block aggregates in parallel and
// releases prefixes (sentinel +1). Device-scope atomics for cross-XCD coherence.
__global__ __launch_bounds__(256)
void scan_one(const int* __restrict__ cnt, int* __restrict__ rowptr,
              int* __restrict__ pos, int n, int nb,
              int* __restrict__ agg, int* __restrict__ pref,
              int* __restrict__ ticket)
{
    __shared__ int s[256];
    __shared__ int m[256];
    __shared__ int ismaster, bcast;
    const int b = blockIdx.x, t = threadIdx.x;
    const int i = b * 256 + t;
    const int v = (i < n) ? cnt[i] : 0;
    s[t] = v;
    __syncthreads();
    for (int o = 1; o < 256; o <<= 1) {
        int u = (t >= o) ? s[t - o] : 0;
        __syncthreads();
        s[t] += u;
        __syncthreads();
    }
    const int incl = s[t];
    if (t == 0) {
        atomicExch(&agg[b], s[255]);
        __threadfence();
        int k = atomicAdd(ticket, 1);
        ismaster = (k == nb - 1);
    }
    __syncthreads();
    if (ismaster) {
        int a = (t < nb) ? atomicAdd(&agg[t], 0) : 0;
        m[t] = a;
        __syncthreads();
        for (int o = 1; o < 256; o <<= 1) {
            int u = (t >= o) ? m[t - o] : 0;
            __syncthreads();
            m[t] += u;
            __syncthreads();
        }
        if (t < nb) atomicExch(&pref[t], (m[t] - a) + 1);   // exclusive, +1 sentinel
        if (t == 0) rowptr[n] = m[nb - 1];
    }
    if (t == 0) {
        int p;
        do { p = atomicAdd(&pref[b], 0); } while (p == 0);
        bcast = p - 1;
    }
    __syncthreads();
    if (i < n) {
        int ex = bcast + incl - v;
        rowptr[i] = ex;
        pos[i] = ex;
    }
}

// ---------------- D3: fused gemmA + scatter (1:2) -----------------------------
__global__ __launch_bounds__(256)
void gemmA_scatter(const unsigned short* __restrict__ Xb,
                   const unsigned short* __restrict__ Wc,
                   const float* __restrict__ mb1, unsigned short* __restrict__ S1Y1,
                   int M, int G,
                   const int* __restrict__ src, const int* __restrict__ dst,
                   const float* __restrict__ w, int* __restrict__ pos,
                   int2* __restrict__ packed, int E)
{
    __shared__ __align__(16) unsigned short SH[16384];
    const int bid = blockIdx.x;
    const int r = bid % 3, g = bid / 3;
    if (bid < 3 * G && r == 0) {
        // sibling-adjacent decode: 4 column tiles of one row panel adjacent (L2)
        const int mBase = (g >> 2) * 128, nBase = (g & 3) * 128;
        gemm_body<true, 3>(Xb, Wc, mb1, S1Y1, M, 256, 512, 0, mBase, nBase, SH);
    } else {
        int sid = (bid < 3 * G) ? (2 * g + (r - 1)) : (2 * G + (bid - 3 * G));
        int e = sid * 256 + threadIdx.x;
        if (e >= E) return;
        int p = atomicAdd(&pos[dst[e]], 1);
        packed[p] = make_int2(src[e], __float_as_int(w[e]));
    }
}

// ---------------- D5: K2 and K4 in one dispatch -------------------------------
__global__ __launch_bounds__(256)
void k2k4(const unsigned short* __restrict__ S1Y1,
          const unsigned short* __restrict__ mw2t,
          const float* __restrict__ mb2, float* __restrict__ out,
          const unsigned short* __restrict__ h1b,
          const unsigned short* __restrict__ w2t,
          unsigned short* __restrict__ gb,
          int M, int ldc, int G)
{
    __shared__ __align__(16) unsigned short SH[16384];
    const int bid = blockIdx.x;
    if (bid < G) {
        // K2: out[:,0:128] = S1 @ mw2 + b2 (fp32)
        gemm_body<false, 2>(S1Y1, mw2t, mb2, out, M, 512, ldc, 0,
                            bid * 128, 0, SH);
    } else {
        // K4: gb = h1 @ W2 (bf16)
        gemm_body<true, 0>(h1b, w2t, nullptr, gb, M, 256, 128, 0,
                           (bid - G) * 128, 0, SH);
    }
}

// ---------------- gather SpMM over bf16 rows, 4-way edge unroll ---------------
template<int TPR, bool RELU, bool DUAL>
__global__ __launch_bounds__(256)
void spmm_csr_bf16(const unsigned short* __restrict__ x,
                   const int* __restrict__ rowptr, const int2* __restrict__ packed,
                   float* __restrict__ outf, unsigned short* __restrict__ outb,
                   int N, int ldx, int ldo, int coff, int ldd)
{
    const int rpb = 256 / TPR;
    const int r = blockIdx.x * rpb + threadIdx.x / TPR;
    const int lane = threadIdx.x % TPR;
    if (r >= N) return;
    const int beg = rowptr[r], end = rowptr[r + 1];
    const unsigned short* xp = x + lane * 8;
    float a0[8] = {0, 0, 0, 0, 0, 0, 0, 0};
    float a1[8] = {0, 0, 0, 0, 0, 0, 0, 0};
    int i = beg;
    for (; i + 3 < end; i += 4) {
        int2 e0 = packed[i], e1 = packed[i + 1], e2 = packed[i + 2], e3 = packed[i + 3];
        uint4 v0 = *(const uint4*)&xp[(size_t)e0.x * ldx];
        uint4 v1 = *(const uint4*)&xp[(size_t)e1.x * ldx];
        uint4 v2 = *(const uint4*)&xp[(size_t)e2.x * ldx];
        uint4 v3 = *(const uint4*)&xp[(size_t)e3.x * ldx];
        float w0 = __int_as_float(e0.y), w1 = __int_as_float(e1.y);
        float w2 = __int_as_float(e2.y), w3 = __int_as_float(e3.y);
        unsigned int s0[4] = {v0.x, v0.y, v0.z, v0.w};
        unsigned int s1[4] = {v1.x, v1.y, v1.z, v1.w};
        unsigned int s2[4] = {v2.x, v2.y, v2.z, v2.w};
        unsigned int s3[4] = {v3.x, v3.y, v3.z, v3.w};
#pragma unroll
        for (int j = 0; j < 4; ++j) {
            a0[2 * j]     = fmaf(w0, __uint_as_float(s0[j] << 16),         a0[2 * j]);
            a0[2 * j + 1] = fmaf(w0, __uint_as_float(s0[j] & 0xFFFF0000u), a0[2 * j + 1]);
            a1[2 * j]     = fmaf(w1, __uint_as_float(s1[j] << 16),         a1[2 * j]);
            a1[2 * j + 1] = fmaf(w1, __uint_as_float(s1[j] & 0xFFFF0000u), a1[2 * j + 1]);
            a0[2 * j]     = fmaf(w2, __uint_as_float(s2[j] << 16),         a0[2 * j]);
            a0[2 * j + 1] = fmaf(w2, __uint_as_float(s2[j] & 0xFFFF0000u), a0[2 * j + 1]);
            a1[2 * j]     = fmaf(w3, __uint_as_float(s3[j] << 16),         a1[2 * j]);
            a1[2 * j + 1] = fmaf(w3, __uint_as_float(s3[j] & 0xFFFF0000u), a1[2 * j + 1]);
        }
    }
    for (; i + 1 < end; i += 2) {
        int2 e0 = packed[i], e1 = packed[i + 1];
        uint4 v0 = *(const uint4*)&xp[(size_t)e0.x * ldx];
        uint4 v1 = *(const uint4*)&xp[(size_t)e1.x * ldx];
        float w0 = __int_as_float(e0.y), w1 = __int_as_float(e1.y);
        unsigned int s0[4] = {v0.x, v0.y, v0.z, v0.w};
        unsigned int s1[4] = {v1.x, v1.y, v1.z, v1.w};
#pragma unroll
        for (int j = 0; j < 4; ++j) {
            a0[2 * j]     = fmaf(w0, __uint_as_float(s0[j] << 16),         a0[2 * j]);
            a0[2 * j + 1] = fmaf(w0, __uint_as_float(s0[j] & 0xFFFF0000u), a0[2 * j + 1]);
            a1[2 * j]     = fmaf(w1, __uint_as_float(s1[j] << 16),         a1[2 * j]);
            a1[2 * j + 1] = fmaf(w1, __uint_as_float(s1[j] & 0xFFFF0000u), a1[2 * j + 1]);
        }
    }
    if (i < end) {
        int2 e0 = packed[i];
        uint4 v0 = *(const uint4*)&xp[(size_t)e0.x * ldx];
        float w0 = __int_as_float(e0.y);
        unsigned int s0[4] = {v0.x, v0.y, v0.z, v0.w};
#pragma unroll
        for (int j = 0; j < 4; ++j) {
            a0[2 * j]     = fmaf(w0, __uint_as_float(s0[j] << 16),         a0[2 * j]);
            a0[2 * j + 1] = fmaf(w0, __uint_as_float(s0[j] & 0xFFFF0000u), a0[2 * j + 1]);
        }
    }
    float acc[8];
#pragma unroll
    for (int j = 0; j < 8; ++j) {
        acc[j] = a0[j] + a1[j];
        if (RELU) acc[j] = fmaxf(acc[j], 0.f);
    }
    float* o = &outf[(size_t)r * ldo + coff + lane * 8];
    *(float4*)o       = make_float4(acc[0], acc[1], acc[2], acc[3]);
    *(float4*)(o + 4) = make_float4(acc[4], acc[5], acc[6], acc[7]);
    if (DUAL) {
        uint4 p;
        p.x = pack2(acc[0], acc[1]); p.y = pack2(acc[2], acc[3]);
        p.z = pack2(acc[4], acc[5]); p.w = pack2(acc[6], acc[7]);
        *(uint4*)&outb[(size_t)r * ldd + lane * 8] = p;
    }
}

// ---------------- launch ------------------------------------------------------
extern "C" void kernel_launch(void* const* d_in, const int* in_sizes, int n_in,
                              void* d_out, int out_size, void* d_ws, size_t ws_size,
                              hipStream_t stream)
{
    const float* X    = (const float*)d_in[0];
    const int*   esrc = (const int*)  d_in[1];
    const int*   edst = (const int*)  d_in[2];
    const float* ew   = (const float*)d_in[3];
    const float* W1   = (const float*)d_in[4];
    const float* W2   = (const float*)d_in[5];
    const float* mw1  = (const float*)d_in[6];
    const float* mb1  = (const float*)d_in[7];
    const float* mw2  = (const float*)d_in[8];
    const float* mb2  = (const float*)d_in[9];

    const int IN_F = 256, HID_F = 256, OUT_F = 128;
    const int N  = in_sizes[0] / IN_F;
    const int E  = in_sizes[1];
    const int LD = OUT_F + HID_F + OUT_F;       // 512
    const int Mp = (N + 127) & ~127;

    float* out = (float*)d_out;

    // workspace (shorts)
    unsigned short* S1Y1  = (unsigned short*)d_ws;          // [Mp][512]: S1 | Y1
    unsigned short* Xb    = S1Y1 + (size_t)Mp * 512;        // [Mp][256] X bf16
    unsigned short* h1b   = Xb;                             // h1 bf16 reuses Xb (dead after gemmA)
    unsigned short* gb    = Xb   + (size_t)Mp * 256;        // [Mp][128]
    unsigned short* warena = gb  + (size_t)Mp * 128;        // [768][256]
    unsigned short* Wc   = warena;                          // [512][256]
    unsigned short* mw2t = warena + 512 * 256;              // [128][256]
    unsigned short* w2t  = warena + 640 * 256;              // [128][256]

    // int region (zeroed by one memset node): rowptr | agg | pref | ticket
    int* iw     = (int*)(warena + 768 * 256);
    int* rowptr = iw;                                       // N+1
    const int aggOff = ((N + 1) + 3) & ~3;
    int* agg    = iw + aggOff;                              // 256
    int* pref   = agg + 256;                                // 256
    int* ticket = pref + 256;                               // 4 (1 used)
    int* pos    = ticket + 4;                               // N
    int2* packed = (int2*)(pos + ((N + 1) & ~1));           // E

    dim3 blk(256);
    const int nb = (N + 255) / 256;         // 196 (<=256 required by scan_one)
    const int mT = Mp / 128;                // 391
    const int He = (E + 255) / 256;         // hist/scatter block count

    // D0: zero rowptr + agg + pref + ticket in one memset node
    hipMemsetAsync(iw, 0, (size_t)(aggOff + 516) * sizeof(int), stream);

    // D1: weights conv + X fp32->bf16 + degree histogram
    prep_all<<<768 + Mp / 8 + He, blk, 0, stream>>>(
        mw1, W1, mw2, W2, warena, X, Xb, N, Mp, edst, rowptr, E);

    // D2: exclusive scan -> rowptr, pos (single dispatch)
    scan_one<<<nb, blk, 0, stream>>>(rowptr, rowptr, pos, N, nb, agg, pref, ticket);

    // D3: fused gemmA + scatter
    {
        const int G = mT * 4;
        int grid = 3 * G + ((He > 2 * G) ? (He - 2 * G) : 0);
        gemmA_scatter<<<grid, blk, 0, stream>>>(
            Xb, Wc, mb1, S1Y1, N, G, esrc, edst, ew, pos, packed, E);
    }

    // D4: SpMM1: h1 = relu(A @ Y1) -> out[:,128:384] fp32 + h1b bf16
    spmm_csr_bf16<32, true, true><<<(N + 7) / 8, blk, 0, stream>>>(
        S1Y1 + 256, rowptr, packed, out, h1b, N, 512, LD, OUT_F, 256);

    // D5: K2 (out[:,0:128] = S1@mw2+b2) and K4 (gb = h1@W2) in one dispatch
    k2k4<<<2 * mT, blk, 0, stream>>>(
        S1Y1, mw2t, mb2, out, h1b, w2t, gb, N, LD, mT);

    // D6: SpMM2: out[:,384:512] = A @ g (fp32)
    spmm_csr_bf16<16, false, false><<<(N + 15) / 16, blk, 0, stream>>>(
        gb, rowptr, packed, out, nullptr, N, 128, LD, OUT_F + HID_F, 0);
}